// Round 16
// baseline (50.658 us; speedup 1.0000x reference)
//
#include <hip/hip_runtime.h>
#include <hip/hip_bf16.h>
#include <math.h>

// TokenCompressor: B=8, N=16384, C=128, BLOCK=32, STRIDE=16 -> nb=1023
//   P[m, 0:256]  = chunk[m] @ W1[0:2048];  P[m,256:512] = chunk[m] @ W1[2048:]
//   h[j] = gelu(P[j,0:256] + P[j+1,256:512] + b1 + posflat@W1); out = h@W2+b2
// R16: the R1-R15 invariant is gemm_time ~ staged_bytes / 9.3 TB/s (L3/fabric
// service), NOT barriers/latency/ratio (all proven flat). So minimize staged
// bytes: BM=128 x BN=512 (full width -> A staged ONCE, 67 MB) x splitK=4
// (grid 256, 1/CU). B (2 MB) is L2-resident; staged 128 MB at L2 speed.
// L3-class staging 393 -> ~195 MB. Machinery unchanged (R15-proven):
// 3-buffer single-barrier counted vmcnt(6), gload_lds, BK=32, 16 steps,
// 8 waves 2m x 4n acc[4][8], LDS 144KB. B-swizzle c4^((row>>1)&3) (2-way
// free on 64B rows); A c8^(row&7).

typedef __attribute__((ext_vector_type(8))) short short8;
typedef __attribute__((ext_vector_type(4))) float f4;

#define OFF_BT   0u                          // 512x2048 bf16 = 2 MB
#define OFF_W2T  (2u << 20)                  // 128x256 bf16 = 64 KB
#define OFF_PART ((2u << 20) + (64u << 10))  // 64x256 f32 = 64 KB
#define OFF_BIAS ((2u << 20) + (128u << 10)) // 256 f32
#define OFF_P    (4u << 20)                  // 4 x (8192x512) bf16 = 32 MB

static __device__ __forceinline__ unsigned short f2bf(float f) {
  union { float f; unsigned u; } v; v.f = f;
  return (unsigned short)((v.u + 0x7FFFu + ((v.u >> 16) & 1u)) >> 16);
}
static __device__ __forceinline__ float bf2f(unsigned short h) {
  union { unsigned u; float f; } v; v.u = ((unsigned)h) << 16;
  return v.f;
}
static __device__ __forceinline__ void gload_lds16(const void* g, void* l) {
  __builtin_amdgcn_global_load_lds(
      (const __attribute__((address_space(1))) void*)g,
      (__attribute__((address_space(3))) void*)l, 16, 0, 0);
}

// ---- k_prep: blocks 0..255: W1 -> Bt (512x2048 bf16, n-major) + bias parts
//              blocks 256..383: W2 (256x128 f32) -> W2t (128x256 bf16, T)
__global__ __launch_bounds__(256) void k_prep(const float* __restrict__ W1,
                                              const float* __restrict__ pos,
                                              const float* __restrict__ W2,
                                              unsigned short* __restrict__ Bt,
                                              unsigned short* __restrict__ W2t,
                                              float* __restrict__ part) {
  __shared__ float T[64][65];
  const int w = blockIdx.x;
  const int t = threadIdx.x;
  if (w >= 256) {
    const int n = w - 256;
    W2t[n * 256 + t] = f2bf(W2[t * 128 + n]);
    return;
  }
  const int h = w >> 7, rem = w & 127, kt = rem >> 2, nt = rem & 3;
  const int krow0 = h * 2048 + kt * 64, col0 = nt * 64;
  const int lr = t >> 2, lc = (t & 3) * 16;
  const float* src = W1 + (size_t)(krow0 + lr) * 256 + col0 + lc;
#pragma unroll
  for (int i = 0; i < 4; ++i) {
    f4 v = *(const f4*)(src + i * 4);
#pragma unroll
    for (int q = 0; q < 4; ++q) T[lr][lc + i * 4 + q] = v[q];
  }
  __syncthreads();
  if (t < 64) {
    float s = 0.f;
#pragma unroll 8
    for (int k = 0; k < 64; ++k) s += T[k][t] * pos[krow0 + k];
    part[(h * 32 + kt) * 256 + col0 + t] = s;
  }
  const int nl = t >> 2, kc = (t & 3) * 16;
  short8 o0, o1;
#pragma unroll
  for (int i = 0; i < 8; ++i) o0[i] = (short)f2bf(T[kc + i][nl]);
#pragma unroll
  for (int i = 0; i < 8; ++i) o1[i] = (short)f2bf(T[kc + 8 + i][nl]);
  unsigned short* dst = Bt + (size_t)(256 * h + col0 + nl) * 2048 + kt * 64 + kc;
  *(short8*)dst = o0;
  *(short8*)(dst + 8) = o1;
}

// ---- k_gemm: Ppart[ksp] (8192x512 bf16) = X(f32)[:,ksp*512:+512] @ Bt^T --
// 128x512 block, BK=32, 16 steps. 512 thr = 8 waves (2m x 4n): wave =
// rows wr*64..+63, cols wc*128..+127, acc[4][8]. Grid 256 = 64mt x 4ksp.
// LDS 3 x (A 128x32 f32 16KB + B 512x32 bf16 32KB) = 144KB.
// Single barrier/step (R15 schedule), counted vmcnt(6).
__global__ __launch_bounds__(512) void k_gemm(const float* __restrict__ X,
                                              const unsigned short* __restrict__ Bt,
                                              const float* __restrict__ part,
                                              const float* __restrict__ b1,
                                              float* __restrict__ biasG,
                                              unsigned short* __restrict__ P) {
  __shared__ __align__(16) char lds[3][49152];  // A f32 16KB | B bf16 32KB
  const int orig = blockIdx.x;
  const int wgid = (orig & 7) * 32 + (orig >> 3);  // bijective (256%8==0)
  const int mt = wgid >> 2;        // 0..63 (XCD keeps 8-mt band)
  const int ksp = wgid & 3;        // 0..3
  const int m0 = mt * 128, k0 = ksp * 512;
  const int t = threadIdx.x;
  const int wid = t >> 6, lane = t & 63;
  const int wr = wid >> 2, wc = wid & 3;  // wave: rows wr*64, cols wc*128

  f4 acc[4][8];
#pragma unroll
  for (int m = 0; m < 4; ++m)
#pragma unroll
    for (int n = 0; n < 8; ++n) acc[m][n] = f4{0.f, 0.f, 0.f, 0.f};

  // 6 gload_lds per thread per step: 2 A (f32) + 4 B (bf16).
  // A slot s=ii*512+t (1024 slots): row=s>>3 (0..127), c8=s&7;
  //   src chunk = c8 ^ (row&7). rows 128B -> 8 chunks, full bank spread.
  // B slot s=ii*512+t (2048 slots): row=s>>2 (0..511), c4=s&3;
  //   src chunk = c4 ^ ((row>>1)&3). rows 64B: bank period 2 rows ->
  //   (row>>1) XOR spreads; frag reads land 2 lanes/bank (free, m136).
#define ISSUE(BUF, KT)                                                     \
  do {                                                                     \
    const int kf = k0 + (KT) * 32;                                         \
    _Pragma("unroll") for (int ii = 0; ii < 2; ++ii) {                     \
      const int s = ii * 512 + t;                                          \
      const int row = s >> 3, c8 = s & 7;                                  \
      gload_lds16(X + (size_t)(m0 + row) * 2048 + kf +                     \
                      ((c8 ^ (row & 7)) << 2),                             \
                  &lds[BUF][ii * 8192 + wid * 1024]);                      \
    }                                                                      \
    _Pragma("unroll") for (int ii = 0; ii < 4; ++ii) {                     \
      const int s = ii * 512 + t;                                          \
      const int row = s >> 2, c4 = s & 3;                                  \
      gload_lds16(Bt + (size_t)row * 2048 + kf +                           \
                      ((c4 ^ ((row >> 1) & 3)) << 3),                      \
                  &lds[BUF][16384 + ii * 8192 + wid * 1024]);              \
    }                                                                      \
  } while (0)

  // per wave per step: 8 A-b128 (f32 lo/hi) + 16 cvt_pk + 8 B-b128 + 32 MFMA
#define COMPUTE(BUF)                                                       \
  do {                                                                     \
    const float* Ab = (const float*)&lds[BUF][0];                          \
    const unsigned short* Bb = (const unsigned short*)&lds[BUF][16384];    \
    short8 af[4], bfv[8];                                                  \
    const int q = lane >> 4;                                               \
    _Pragma("unroll") for (int m = 0; m < 4; ++m) {                        \
      const int row = wr * 64 + m * 16 + (lane & 15);                      \
      const int e = row & 7;                                               \
      f4 lo = *(const f4*)(Ab + row * 32 + (((2 * q) ^ e) << 2));          \
      f4 hi = *(const f4*)(Ab + row * 32 + (((2 * q + 1) ^ e) << 2));      \
      union { short8 s8; unsigned u[4]; } pk;                              \
      asm("v_cvt_pk_bf16_f32 %0, %1, %2" : "=v"(pk.u[0])                   \
          : "v"(lo[0]), "v"(lo[1]));                                       \
      asm("v_cvt_pk_bf16_f32 %0, %1, %2" : "=v"(pk.u[1])                   \
          : "v"(lo[2]), "v"(lo[3]));                                       \
      asm("v_cvt_pk_bf16_f32 %0, %1, %2" : "=v"(pk.u[2])                   \
          : "v"(hi[0]), "v"(hi[1]));                                       \
      asm("v_cvt_pk_bf16_f32 %0, %1, %2" : "=v"(pk.u[3])                   \
          : "v"(hi[2]), "v"(hi[3]));                                       \
      af[m] = pk.s8;                                                       \
    }                                                                      \
    _Pragma("unroll") for (int n = 0; n < 8; ++n) {                        \
      const int row = wc * 128 + n * 16 + (lane & 15);                     \
      bfv[n] = *(const short8*)(Bb + row * 32 +                            \
                                ((q ^ ((row >> 1) & 3)) << 3));            \
    }                                                                      \
    __builtin_amdgcn_s_setprio(1);                                         \
    _Pragma("unroll") for (int m = 0; m < 4; ++m)                          \
      _Pragma("unroll") for (int n = 0; n < 8; ++n)                        \
        acc[m][n] = __builtin_amdgcn_mfma_f32_16x16x32_bf16(               \
            af[m], bfv[n], acc[m][n], 0, 0, 0);                            \
    __builtin_amdgcn_s_setprio(0);                                         \
  } while (0)

  // prologue: tiles 0,1 in flight (12 DMAs); wait tile 0 (leave 6)
  ISSUE(0, 0);
  ISSUE(1, 1);
  __builtin_amdgcn_sched_barrier(0);
  asm volatile("s_waitcnt vmcnt(6)" ::: "memory");
  __builtin_amdgcn_s_barrier();
  __builtin_amdgcn_sched_barrier(0);

  // single-barrier steady state (R15): step kt issues tile kt+2 into the
  // buffer released by barrier kt-1; one vmcnt(6)+barrier proves tile kt+1
  // landed and all waves finished reading tile kt.
  for (int kt = 0; kt < 16; ++kt) {
    if (kt < 14) ISSUE((kt + 2) % 3, kt + 2);
    COMPUTE(kt % 3);
    __builtin_amdgcn_sched_barrier(0);
    if (kt < 15) {
      if (kt < 14) asm volatile("s_waitcnt vmcnt(6)" ::: "memory");
      else         asm volatile("s_waitcnt vmcnt(0)" ::: "memory");
      __builtin_amdgcn_s_barrier();
      __builtin_amdgcn_sched_barrier(0);
    }
  }
#undef ISSUE
#undef COMPUTE

  // epilogue A: bias vector (threads 0..255; all blocks write same values)
  if (t < 256) {
    float s = b1[t];
#pragma unroll 8
    for (int g = 0; g < 64; ++g) s += part[g * 256 + t];
    biasG[t] = s;
  }

  // epilogue B: partial write. C/D layout: col=lane&15, row=(lane>>4)*4+reg
  unsigned short* Pp = P + (size_t)ksp * (8192 * 512);
  const int mb = m0 + wr * 64, nb = wc * 128;
#pragma unroll
  for (int m = 0; m < 4; ++m)
#pragma unroll
    for (int n = 0; n < 8; ++n) {
      const int row0 = mb + m * 16 + ((lane >> 4) << 2);
      const int col = nb + n * 16 + (lane & 15);
#pragma unroll
      for (int r = 0; r < 4; ++r)
        Pp[(size_t)(row0 + r) * 512 + col] = f2bf(acc[m][n][r]);
    }
}

// ---- k_comb: h=gelu(sum_ksp(P0,P1)+bias); out = h@W2 + b2 ---------------
__global__ __launch_bounds__(256) void k_comb(const unsigned short* __restrict__ P,
                                              const unsigned short* __restrict__ W2t,
                                              const float* __restrict__ biasG,
                                              const float* __restrict__ b2,
                                              float* __restrict__ out) {
  __shared__ unsigned short W2s[128 * 256];
  __shared__ unsigned short Hs[32 * 256];
  __shared__ float biasS[256];
  const int wg = blockIdx.x;
  const int b = wg >> 5, jt = wg & 31;
  const int j0 = jt * 32;
  const int t = threadIdx.x;

  biasS[t] = biasG[t];  // finished vector (k_gemm epilogue), 1KB
  {  // stage W2t (rows 512B; swizzle slot ^= row&7)
    const int row = t >> 1, halfc = (t & 1) * 128;
    const unsigned short* src = W2t + row * 256 + halfc;
    const int cbw = halfc >> 3;
#pragma unroll
    for (int i = 0; i < 16; ++i) {
      short8 v = *(const short8*)(src + i * 8);
      const int c = (cbw + i) ^ (row & 7);
      *(short8*)&W2s[row * 256 + c * 8] = v;
    }
  }
  __syncthreads();
  {  // h rows: thread = (row r, 32-col segment); sum 4 split-K partials
    const int r = t >> 3, seg = t & 7;
    const int j = j0 + r;
    const size_t m = (size_t)b * 1024 + j;
    const size_t mp1 = (j < 1023) ? m + 1 : m;  // clamp (masked later)
    const float* bs = biasS + seg * 32;
    const int cbh = seg * 4;
#pragma unroll
    for (int i = 0; i < 4; ++i) {
      float f0[8];
#pragma unroll
      for (int q = 0; q < 8; ++q) f0[q] = bs[i * 8 + q];
#pragma unroll
      for (int ksp = 0; ksp < 4; ++ksp) {
        const unsigned short* Pk = P + (size_t)ksp * (8192 * 512);
        short8 v0 = *(const short8*)(Pk + m * 512 + seg * 32 + i * 8);
        short8 v1 = *(const short8*)(Pk + mp1 * 512 + 256 + seg * 32 + i * 8);
#pragma unroll
        for (int q = 0; q < 8; ++q)
          f0[q] += bf2f((unsigned short)v0[q]) + bf2f((unsigned short)v1[q]);
      }
      short8 pk;
#pragma unroll
      for (int q = 0; q < 8; ++q) {
        float g = 0.5f * f0[q] * (1.f + erff(f0[q] * 0.70710678118f));
        pk[q] = (short)f2bf(g);
      }
      const int c = (cbh + i) ^ (r & 7);
      *(short8*)&Hs[r * 256 + c * 8] = pk;
    }
  }
  __syncthreads();

  const int wid = t >> 6, lane = t & 63;
  f4 acc[2][2];
#pragma unroll
  for (int i = 0; i < 2; ++i)
#pragma unroll
    for (int j = 0; j < 2; ++j) acc[i][j] = f4{0.f, 0.f, 0.f, 0.f};

#pragma unroll
  for (int ks = 0; ks < 8; ++ks) {
    short8 af[2], bfr[2];
    const int cc = ks * 4 + (lane >> 4);
#pragma unroll
    for (int f = 0; f < 2; ++f) {
      const int ra = f * 16 + (lane & 15);
      af[f] = *(const short8*)&Hs[ra * 256 + ((cc ^ (ra & 7)) << 3)];
      const int rb = wid * 32 + f * 16 + (lane & 15);
      bfr[f] = *(const short8*)&W2s[rb * 256 + ((cc ^ (rb & 7)) << 3)];
    }
#pragma unroll
    for (int i = 0; i < 2; ++i)
#pragma unroll
      for (int j = 0; j < 2; ++j)
        acc[i][j] = __builtin_amdgcn_mfma_f32_16x16x32_bf16(af[i], bfr[j],
                                                            acc[i][j], 0, 0, 0);
  }
#pragma unroll
  for (int i = 0; i < 2; ++i)
#pragma unroll
    for (int j = 0; j < 2; ++j) {
      const int row0 = i * 16 + ((lane >> 4) << 2);
      const int col = wid * 32 + j * 16 + (lane & 15);
      const float bb = b2[col];
#pragma unroll
      for (int r = 0; r < 4; ++r) {
        const int jj = j0 + row0 + r;
        if (jj < 1023)
          out[((size_t)b * 1023 + jj) * 128 + col] = acc[i][j][r] + bb;
      }
    }
}

extern "C" void kernel_launch(void* const* d_in, const int* in_sizes, int n_in,
                              void* d_out, int out_size, void* d_ws, size_t ws_size,
                              hipStream_t stream) {
  const float* x   = (const float*)d_in[0];
  const float* pos = (const float*)d_in[1];
  const float* W1  = (const float*)d_in[2];
  const float* b1  = (const float*)d_in[3];
  const float* W2  = (const float*)d_in[4];
  const float* b2  = (const float*)d_in[5];
  float* out = (float*)d_out;
  char* ws = (char*)d_ws;
  unsigned short* Bt  = (unsigned short*)(ws + OFF_BT);
  unsigned short* W2t = (unsigned short*)(ws + OFF_W2T);
  float* part         = (float*)(ws + OFF_PART);
  float* biasG        = (float*)(ws + OFF_BIAS);
  unsigned short* P   = (unsigned short*)(ws + OFF_P);

  k_prep<<<384, 256, 0, stream>>>(W1, pos, W2, Bt, W2t, part);
  k_gemm<<<256, 512, 0, stream>>>(x, Bt, part, b1, biasG, P);
  k_comb<<<256, 256, 0, stream>>>(P, W2t, biasG, b2, out);
}

// Round 17
// 49.241 us; speedup vs baseline: 1.0288x; 1.0288x over previous
//
#include <hip/hip_runtime.h>
#include <hip/hip_bf16.h>
#include <math.h>

// TokenCompressor: B=8, N=16384, C=128, BLOCK=32, STRIDE=16 -> nb=1023
// Decomposition: chunks c of 16 tokens; A = x.view(8192, 2048) (contiguous!)
//   P[m, 0:256]  = chunk[m] @ W1[0:2048]
//   P[m, 256:512]= chunk[m] @ W1[2048:4096]
//   h[j] = gelu(P[j,0:256] + P[j+1,256:512] + b1 + posflat@W1)
//   out[j] = h[j] @ W2 + b2
// R17 = R15 restored (measured best, 49.38us). R16's A-once/splitK=4 variant
// improved gemm 42.5->39.4 but its P-partial traffic cost ~11us elsewhere;
// net worse. 16 structural variants all sit on the same staging-service
// envelope (~130 cyc per staged KB under the 2-barrier cadence); R15 is the
// Pareto point: minimal auxiliary traffic (8MB P write + 16MB comb read),
// single-barrier steady state, 3-buffer counted-vmcnt pipeline, bias folded
// into the gemm epilogue.

typedef __attribute__((ext_vector_type(8))) short short8;
typedef __attribute__((ext_vector_type(4))) float f4;

#define OFF_BT   0u                          // 512x2048 bf16 = 2 MB
#define OFF_W2T  (2u << 20)                  // 128x256 bf16 = 64 KB
#define OFF_PART ((2u << 20) + (64u << 10))  // 64x256 f32 = 64 KB
#define OFF_BIAS ((2u << 20) + (128u << 10)) // 256 f32
#define OFF_P    (4u << 20)                  // 8192x512 bf16 = 8 MB

static __device__ __forceinline__ unsigned short f2bf(float f) {
  union { float f; unsigned u; } v; v.f = f;
  return (unsigned short)((v.u + 0x7FFFu + ((v.u >> 16) & 1u)) >> 16);
}
static __device__ __forceinline__ float bf2f(unsigned short h) {
  union { unsigned u; float f; } v; v.u = ((unsigned)h) << 16;
  return v.f;
}
static __device__ __forceinline__ void gload_lds16(const void* g, void* l) {
  __builtin_amdgcn_global_load_lds(
      (const __attribute__((address_space(1))) void*)g,
      (__attribute__((address_space(3))) void*)l, 16, 0, 0);
}

// ---- k_prep: blocks 0..255: W1 -> Bt (512x2048 bf16, n-major) + bias parts
//              blocks 256..383: W2 (256x128 f32) -> W2t (128x256 bf16, T)
__global__ __launch_bounds__(256) void k_prep(const float* __restrict__ W1,
                                              const float* __restrict__ pos,
                                              const float* __restrict__ W2,
                                              unsigned short* __restrict__ Bt,
                                              unsigned short* __restrict__ W2t,
                                              float* __restrict__ part) {
  __shared__ float T[64][65];
  const int w = blockIdx.x;
  const int t = threadIdx.x;
  if (w >= 256) {
    const int n = w - 256;
    W2t[n * 256 + t] = f2bf(W2[t * 128 + n]);
    return;
  }
  const int h = w >> 7, rem = w & 127, kt = rem >> 2, nt = rem & 3;
  const int krow0 = h * 2048 + kt * 64, col0 = nt * 64;
  const int lr = t >> 2, lc = (t & 3) * 16;
  const float* src = W1 + (size_t)(krow0 + lr) * 256 + col0 + lc;
#pragma unroll
  for (int i = 0; i < 4; ++i) {
    f4 v = *(const f4*)(src + i * 4);
#pragma unroll
    for (int q = 0; q < 4; ++q) T[lr][lc + i * 4 + q] = v[q];
  }
  __syncthreads();
  if (t < 64) {
    float s = 0.f;
#pragma unroll 8
    for (int k = 0; k < 64; ++k) s += T[k][t] * pos[krow0 + k];
    part[(h * 32 + kt) * 256 + col0 + t] = s;
  }
  const int nl = t >> 2, kc = (t & 3) * 16;
  short8 o0, o1;
#pragma unroll
  for (int i = 0; i < 8; ++i) o0[i] = (short)f2bf(T[kc + i][nl]);
#pragma unroll
  for (int i = 0; i < 8; ++i) o1[i] = (short)f2bf(T[kc + 8 + i][nl]);
  unsigned short* dst = Bt + (size_t)(256 * h + col0 + nl) * 2048 + kt * 64 + kc;
  *(short8*)dst = o0;
  *(short8*)(dst + 8) = o1;
}

// ---- k_gemm: P (8192x512 bf16) = X(f32) @ Bt^T, full K=2048 -------------
// 128x128 tile, BK=64, 32 steps. 512 thr = 8 waves (4x2), per-wave 32x64
// (acc[2][4]). Grid 256 (1/CU). 3 LDS buffers x (A f32 32KB + B bf16 16KB)
// = 144KB. Single barrier per step. Epilogue finalizes bias.
__global__ __launch_bounds__(512) void k_gemm(const float* __restrict__ X,
                                              const unsigned short* __restrict__ Bt,
                                              const float* __restrict__ part,
                                              const float* __restrict__ b1,
                                              float* __restrict__ biasG,
                                              unsigned short* __restrict__ P) {
  __shared__ __align__(16) char lds[3][49152];  // A f32 32KB | B bf16 16KB
  const int orig = blockIdx.x;
  const int wgid = (orig & 7) * 32 + (orig >> 3);  // bijective (256%8==0)
  const int mt = wgid >> 2, nt = wgid & 3;  // XCD keeps 8-mt band, all nt
  const int m0 = mt * 128, n0 = nt * 128;
  const int t = threadIdx.x;
  const int wid = t >> 6, lane = t & 63;
  const int wr = wid >> 1, wc = wid & 1;  // wave tile: rows wr*32, cols wc*64

  f4 acc[2][4];
#pragma unroll
  for (int m = 0; m < 2; ++m)
#pragma unroll
    for (int n = 0; n < 4; ++n) acc[m][n] = f4{0.f, 0.f, 0.f, 0.f};

  // 6 gload_lds per thread per tile: 4 A (f32) + 2 B (bf16).
  // A slot s=ii*512+t: row=s>>4, c16=s&15, src chunk = c16 ^ e(row),
  //   e = ((row&7)<<1)|((row>>3)&1) (full 16-chunk spread -> 32 banks).
  // B slot s=ii*512+t: row=s>>3, c8=s&7, src chunk = c8 ^ (row&7).
#define ISSUE(BUF, KT)                                                     \
  do {                                                                     \
    const int kf = (KT) * 64;                                              \
    _Pragma("unroll") for (int ii = 0; ii < 4; ++ii) {                     \
      const int s = ii * 512 + t;                                          \
      const int row = s >> 4, c16 = s & 15;                                \
      const int e = ((row & 7) << 1) | ((row >> 3) & 1);                   \
      gload_lds16(X + (size_t)(m0 + row) * 2048 + kf + ((c16 ^ e) << 2),   \
                  &lds[BUF][ii * 8192 + wid * 1024]);                      \
    }                                                                      \
    _Pragma("unroll") for (int ii = 0; ii < 2; ++ii) {                     \
      const int s = ii * 512 + t;                                          \
      const int row = s >> 3, c8 = s & 7;                                  \
      gload_lds16(Bt + (size_t)(n0 + row) * 2048 + kf +                    \
                      ((c8 ^ (row & 7)) << 3),                             \
                  &lds[BUF][32768 + ii * 8192 + wid * 1024]);              \
    }                                                                      \
  } while (0)

  // per wave per step: 8 A-b128 (f32 lo/hi) + 16 cvt_pk + 8 B-b128 + 16 MFMA
#define COMPUTE(BUF)                                                       \
  do {                                                                     \
    const float* Ab = (const float*)&lds[BUF][0];                          \
    const unsigned short* Bb = (const unsigned short*)&lds[BUF][32768];    \
    _Pragma("unroll") for (int ks = 0; ks < 2; ++ks) {                     \
      short8 af[2];                                                        \
      short8 bfv[4];                                                       \
      _Pragma("unroll") for (int m = 0; m < 2; ++m) {                      \
        const int row = wr * 32 + m * 16 + (lane & 15);                    \
        const int e = ((row & 7) << 1) | ((row >> 3) & 1);                 \
        const int cp = ks * 8 + (lane >> 4) * 2;                           \
        f4 lo = *(const f4*)(Ab + row * 64 + ((cp ^ e) << 2));             \
        f4 hi = *(const f4*)(Ab + row * 64 + (((cp + 1) ^ e) << 2));       \
        union { short8 s8; unsigned u[4]; } pk;                            \
        asm("v_cvt_pk_bf16_f32 %0, %1, %2" : "=v"(pk.u[0])                 \
            : "v"(lo[0]), "v"(lo[1]));                                     \
        asm("v_cvt_pk_bf16_f32 %0, %1, %2" : "=v"(pk.u[1])                 \
            : "v"(lo[2]), "v"(lo[3]));                                     \
        asm("v_cvt_pk_bf16_f32 %0, %1, %2" : "=v"(pk.u[2])                 \
            : "v"(hi[0]), "v"(hi[1]));                                     \
        asm("v_cvt_pk_bf16_f32 %0, %1, %2" : "=v"(pk.u[3])                 \
            : "v"(hi[2]), "v"(hi[3]));                                     \
        af[m] = pk.s8;                                                     \
      }                                                                    \
      _Pragma("unroll") for (int n = 0; n < 4; ++n) {                      \
        const int row = wc * 64 + n * 16 + (lane & 15);                    \
        const int ch = ks * 4 + (lane >> 4);                               \
        bfv[n] = *(const short8*)(Bb + row * 64 +                          \
                                  ((ch ^ (row & 7)) << 3));                \
      }                                                                    \
      __builtin_amdgcn_s_setprio(1);                                       \
      _Pragma("unroll") for (int m = 0; m < 2; ++m)                        \
        _Pragma("unroll") for (int n = 0; n < 4; ++n)                      \
          acc[m][n] = __builtin_amdgcn_mfma_f32_16x16x32_bf16(             \
              af[m], bfv[n], acc[m][n], 0, 0, 0);                          \
      __builtin_amdgcn_s_setprio(0);                                       \
    }                                                                      \
  } while (0)

  // prologue: tiles 0,1 in flight (12 DMAs); wait tile 0 (leave 6)
  ISSUE(0, 0);
  ISSUE(1, 1);
  __builtin_amdgcn_sched_barrier(0);
  asm volatile("s_waitcnt vmcnt(6)" ::: "memory");
  __builtin_amdgcn_s_barrier();
  __builtin_amdgcn_sched_barrier(0);

  // single-barrier steady state:
  //   step kt: ISSUE((kt+2)%3, kt+2)  [buf released by barrier kt-1]
  //            COMPUTE(kt%3)          [tile kt landed: proven at barrier kt-1]
  //            vmcnt(6)+barrier       [tile kt+1 landed; readers of kt done]
  for (int kt = 0; kt < 32; ++kt) {
    if (kt < 30) ISSUE((kt + 2) % 3, kt + 2);
    COMPUTE(kt % 3);
    __builtin_amdgcn_sched_barrier(0);
    if (kt < 31) {
      if (kt < 30) asm volatile("s_waitcnt vmcnt(6)" ::: "memory");
      else         asm volatile("s_waitcnt vmcnt(0)" ::: "memory");
      __builtin_amdgcn_s_barrier();
      __builtin_amdgcn_sched_barrier(0);
    }
  }
#undef ISSUE
#undef COMPUTE

  // epilogue A: bias slice (threads 0..127): bias[n] = b1[n] + sum_g part
  if (t < 128) {
    const int n = ((nt & 1) << 7) + t;
    float s = b1[n];
#pragma unroll 8
    for (int g = 0; g < 64; ++g) s += part[g * 256 + n];
    biasG[n] = s;
  }

  // epilogue B: P bf16. C/D layout: col=lane&15, row=(lane>>4)*4+reg
  const int mb = m0 + wr * 32, nb = n0 + wc * 64;
#pragma unroll
  for (int m = 0; m < 2; ++m)
#pragma unroll
    for (int n = 0; n < 4; ++n) {
      const int row0 = mb + m * 16 + ((lane >> 4) << 2);
      const int col = nb + n * 16 + (lane & 15);
#pragma unroll
      for (int r = 0; r < 4; ++r)
        P[(size_t)(row0 + r) * 512 + col] = f2bf(acc[m][n][r]);
    }
}

// ---- k_comb: h=gelu(P0+P1+bias); out = h@W2 + b2 -----------------------
__global__ __launch_bounds__(256) void k_comb(const unsigned short* __restrict__ P,
                                              const unsigned short* __restrict__ W2t,
                                              const float* __restrict__ biasG,
                                              const float* __restrict__ b2,
                                              float* __restrict__ out) {
  __shared__ unsigned short W2s[128 * 256];
  __shared__ unsigned short Hs[32 * 256];
  __shared__ float biasS[256];
  const int wg = blockIdx.x;
  const int b = wg >> 5, jt = wg & 31;
  const int j0 = jt * 32;
  const int t = threadIdx.x;

  biasS[t] = biasG[t];  // finished vector (k_gemm epilogue), 1KB
  {  // stage W2t (rows 512B; swizzle slot ^= row&7)
    const int row = t >> 1, halfc = (t & 1) * 128;
    const unsigned short* src = W2t + row * 256 + halfc;
    const int cbw = halfc >> 3;
#pragma unroll
    for (int i = 0; i < 16; ++i) {
      short8 v = *(const short8*)(src + i * 8);
      const int c = (cbw + i) ^ (row & 7);
      *(short8*)&W2s[row * 256 + c * 8] = v;
    }
  }
  __syncthreads();
  {  // h rows: thread = (row r, 32-col segment)
    const int r = t >> 3, seg = t & 7;
    const int j = j0 + r;
    const size_t m = (size_t)b * 1024 + j;
    const size_t mp1 = (j < 1023) ? m + 1 : m;  // clamp (masked later)
    const unsigned short* p0 = P + m * 512 + seg * 32;
    const unsigned short* p1 = P + mp1 * 512 + 256 + seg * 32;
    const float* bs = biasS + seg * 32;
    const int cbh = seg * 4;
#pragma unroll
    for (int i = 0; i < 4; ++i) {
      short8 v0 = *(const short8*)(p0 + i * 8);
      short8 v1 = *(const short8*)(p1 + i * 8);
      short8 pk;
#pragma unroll
      for (int q = 0; q < 8; ++q) {
        float f = bf2f((unsigned short)v0[q]) + bf2f((unsigned short)v1[q]) +
                  bs[i * 8 + q];
        float g = 0.5f * f * (1.f + erff(f * 0.70710678118f));
        pk[q] = (short)f2bf(g);
      }
      const int c = (cbh + i) ^ (r & 7);
      *(short8*)&Hs[r * 256 + c * 8] = pk;
    }
  }
  __syncthreads();

  const int wid = t >> 6, lane = t & 63;
  f4 acc[2][2];
#pragma unroll
  for (int i = 0; i < 2; ++i)
#pragma unroll
    for (int j = 0; j < 2; ++j) acc[i][j] = f4{0.f, 0.f, 0.f, 0.f};

#pragma unroll
  for (int ks = 0; ks < 8; ++ks) {
    short8 af[2], bfr[2];
    const int cc = ks * 4 + (lane >> 4);
#pragma unroll
    for (int f = 0; f < 2; ++f) {
      const int ra = f * 16 + (lane & 15);
      af[f] = *(const short8*)&Hs[ra * 256 + ((cc ^ (ra & 7)) << 3)];
      const int rb = wid * 32 + f * 16 + (lane & 15);
      bfr[f] = *(const short8*)&W2s[rb * 256 + ((cc ^ (rb & 7)) << 3)];
    }
#pragma unroll
    for (int i = 0; i < 2; ++i)
#pragma unroll
      for (int j = 0; j < 2; ++j)
        acc[i][j] = __builtin_amdgcn_mfma_f32_16x16x32_bf16(af[i], bfr[j],
                                                            acc[i][j], 0, 0, 0);
  }
#pragma unroll
  for (int i = 0; i < 2; ++i)
#pragma unroll
    for (int j = 0; j < 2; ++j) {
      const int row0 = i * 16 + ((lane >> 4) << 2);
      const int col = wid * 32 + j * 16 + (lane & 15);
      const float bb = b2[col];
#pragma unroll
      for (int r = 0; r < 4; ++r) {
        const int jj = j0 + row0 + r;
        if (jj < 1023)
          out[((size_t)b * 1023 + jj) * 128 + col] = acc[i][j][r] + bb;
      }
    }
}

extern "C" void kernel_launch(void* const* d_in, const int* in_sizes, int n_in,
                              void* d_out, int out_size, void* d_ws, size_t ws_size,
                              hipStream_t stream) {
  const float* x   = (const float*)d_in[0];
  const float* pos = (const float*)d_in[1];
  const float* W1  = (const float*)d_in[2];
  const float* b1  = (const float*)d_in[3];
  const float* W2  = (const float*)d_in[4];
  const float* b2  = (const float*)d_in[5];
  float* out = (float*)d_out;
  char* ws = (char*)d_ws;
  unsigned short* Bt  = (unsigned short*)(ws + OFF_BT);
  unsigned short* W2t = (unsigned short*)(ws + OFF_W2T);
  float* part         = (float*)(ws + OFF_PART);
  float* biasG        = (float*)(ws + OFF_BIAS);
  unsigned short* P   = (unsigned short*)(ws + OFF_P);

  k_prep<<<384, 256, 0, stream>>>(W1, pos, W2, Bt, W2t, part);
  k_gemm<<<256, 512, 0, stream>>>(x, Bt, part, b1, biasG, P);
  k_comb<<<256, 256, 0, stream>>>(P, W2t, biasG, b2, out);
}